// Round 8
// baseline (57446.698 us; speedup 1.0000x reference)
//
#include <hip/hip_runtime.h>
#include <hip/hip_fp16.h>

#define Bn 256
#define Sn 128
#define Hn 512
#define G4 2048
#define NBLK 512
#define NTHR 1024
#define HSTR 516   // padded LDS stride

typedef float f4v __attribute__((ext_vector_type(4)));
typedef unsigned u4v __attribute__((ext_vector_type(4)));

__device__ __forceinline__ float sigf(float x){
    float e = expf(-fabsf(x));
    float d = 1.f + e;
    return x >= 0.f ? 1.f/d : e/d;
}

// Agent-scope coherent scalar access (coherence point, no L2 inv/wb).
__device__ __forceinline__ float cload(const float* p){
    return __hip_atomic_load((float*)p, __ATOMIC_RELAXED, __HIP_MEMORY_SCOPE_AGENT);
}
__device__ __forceinline__ void cstore(float* p, float v){
    __hip_atomic_store(p, v, __ATOMIC_RELAXED, __HIP_MEMORY_SCOPE_AGENT);
}

// ---- per-group (16 blocks, one batch-tile) barrier: relaxed, no cache ops.
__device__ __forceinline__ void gbar(unsigned* cnt, unsigned k){
    __syncthreads();
    if (threadIdx.x == 0) {
        __hip_atomic_fetch_add(cnt, 1u, __ATOMIC_RELAXED, __HIP_MEMORY_SCOPE_AGENT);
        while (__hip_atomic_load(cnt, __ATOMIC_RELAXED, __HIP_MEMORY_SCOPE_AGENT) < 16u*k)
            __builtin_amdgcn_s_sleep(1);
        asm volatile("" ::: "memory");
    }
    __syncthreads();
}
// Transition barrier (once): release (wbl2) + acquire (inv) for w1enc handoff.
__device__ __forceinline__ void gbar_sys(unsigned* cnt, unsigned k){
    __syncthreads();
    if (threadIdx.x == 0) {
        __hip_atomic_fetch_add(cnt, 1u, __ATOMIC_RELEASE, __HIP_MEMORY_SCOPE_AGENT);
        while (__hip_atomic_load(cnt, __ATOMIC_RELAXED, __HIP_MEMORY_SCOPE_AGENT) < 16u*k)
            __builtin_amdgcn_s_sleep(1);
        (void)__hip_atomic_load(cnt, __ATOMIC_ACQUIRE, __HIP_MEMORY_SCOPE_AGENT);
    }
    __syncthreads();
}

// ---- rank-1 collapse of the input-side GEMMs (F_IN == 1) ----
__global__ void precompute_kernel(
    const float* __restrict__ Wih_e, const float* __restrict__ We_e,
    const float* __restrict__ be_e,  const float* __restrict__ b_e,
    const float* __restrict__ Wih_d, const float* __restrict__ We_d,
    const float* __restrict__ be_d,  const float* __restrict__ b_d,
    float* __restrict__ p1, float* __restrict__ p0,
    float* __restrict__ r1, float* __restrict__ r0)
{
    int j = blockIdx.x*blockDim.x + threadIdx.x;   // 0..4095
    bool dec = j >= G4;
    int jj = dec ? j - G4 : j;
    const float* Wih = dec ? Wih_d : Wih_e;
    const float* We  = dec ? We_d  : We_e;
    const float* be  = dec ? be_d  : be_e;
    const float* bb  = dec ? b_d   : b_e;
    float s1 = 0.f, s0 = 0.f;
    for (int k = 0; k < Hn; ++k) {
        float w = Wih[jj*Hn + k];
        s1 += w * We[k];
        s0 += w * be[k];
    }
    s0 += bb[jj];
    if (dec) { r1[jj] = s1; r0[jj] = s0; }
    else     { p1[jj] = s1; p0[jj] = s0; }
}

// ---- whole pointer network: 512 blocks (32 groups x 16), 2 blocks/CU ----
// Block (bt=blk>>4, grp=blk&15): batches [bt*8, bt*8+8), h-slice [grp*32,+32).
// Threads: tb=tid&7 (batch), hh=(tid>>3)&31 (h), ks=tid>>8 (k-quarter).
// Attn: blocks grp<8 handle batch bt*8+grp; grp>=8 idle (co-resident group
// fills the CU). Group barriers only; one release/acquire at enc->dec.
template<bool WEF>
__global__ __launch_bounds__(NTHR, 8) void ptrnet_kernel(
    const float* __restrict__ xseq,
    const float* __restrict__ Whh_e, const float* __restrict__ Whh_d,
    const float* __restrict__ W1, const float* __restrict__ b1,
    const float* __restrict__ W2, const float* __restrict__ b2,
    const float* __restrict__ vv,
    const float* __restrict__ p1, const float* __restrict__ p0,
    const float* __restrict__ r1, const float* __restrict__ r0,
    float* __restrict__ hb0, float* __restrict__ hb1,
    float* __restrict__ cbuf, float* __restrict__ qbuf,
    float* __restrict__ x_in, void* __restrict__ w1enc,
    unsigned* __restrict__ barb,
    float* __restrict__ out_scores, float* __restrict__ out_ptr)
{
    __shared__ float smem[8*HSTR + 3*256*5 + 16];   // ~31.5 KB -> 2 blocks/CU
    float* hs  = smem;                 // [8][HSTR] h-tile
    float* red = smem + 8*HSTR;        // split-k partials (3 quarters x 256 x 5)
    float* qs  = smem;                 // attn aliases (phases disjoint)
    float* vs  = smem + Hn;
    float* us  = smem + 2*Hn;          // 128 logits
    float* rr  = smem + 2*Hn + Sn + 8; // {max, log-sum-exp}

    const int blk = blockIdx.x;
    const int tid = threadIdx.x;
    const int bt  = blk >> 4, grp = blk & 15;
    const int b0  = bt << 3;           // 8 batches per group
    const int tb  = tid & 7;
    const int hh  = (tid >> 3) & 31;
    const int ks  = tid >> 8;          // 0..3
    const int hg  = (grp << 5) + hh;
    const int kofs = ks << 7;          // 128-float quarter
    const int ridx = (tid & 255) * 5;
    unsigned* gcnt = barb + bt*64;
    unsigned bk = 0;
    float* hprev = hb0;
    float* hnext = hb1;

#define STAGE_H(SRC) do { \
    for (int i_ = tid; i_ < 8*Hn; i_ += NTHR) { \
        int r_ = i_ >> 9, k_ = i_ & (Hn-1); \
        hs[r_*HSTR + k_] = cload((SRC) + (size_t)(b0+r_)*Hn + k_); \
    } __syncthreads(); } while(0)

    // ================= encoder: t = 0..128 (t==128 emits only w1enc[127]) ===
    for (int t = 0; t <= Sn; ++t) {
        STAGE_H(hprev);
        float a0=0.f,a1=0.f,a2=0.f,a3=0.f,a4=0.f;
        {
            const float* hrow = hs + tb*HSTR + kofs;
            const float* w0 = Whh_e + (size_t)hg*Hn          + kofs;
            const float* w1r= Whh_e + (size_t)(Hn+hg)*Hn     + kofs;
            const float* w2r= Whh_e + (size_t)(2*Hn+hg)*Hn   + kofs;
            const float* w3r= Whh_e + (size_t)(3*Hn+hg)*Hn   + kofs;
            const float* w4r= W1    + (size_t)hg*Hn          + kofs;
            for (int i = 0; i < 128; i += 4) {
                float4 hv = *(const float4*)(hrow + i);
                float4 x0 = *(const float4*)(w0 + i);
                float4 x1 = *(const float4*)(w1r + i);
                float4 x2 = *(const float4*)(w2r + i);
                float4 x3 = *(const float4*)(w3r + i);
                float4 x4 = *(const float4*)(w4r + i);
                a0 += hv.x*x0.x + hv.y*x0.y + hv.z*x0.z + hv.w*x0.w;
                a1 += hv.x*x1.x + hv.y*x1.y + hv.z*x1.z + hv.w*x1.w;
                a2 += hv.x*x2.x + hv.y*x2.y + hv.z*x2.z + hv.w*x2.w;
                a3 += hv.x*x3.x + hv.y*x3.y + hv.z*x3.z + hv.w*x3.w;
                a4 += hv.x*x4.x + hv.y*x4.y + hv.z*x4.z + hv.w*x4.w;
            }
        }
        if (ks) {
            float* rp = red + (ks-1)*1280 + ridx;
            rp[0]=a0; rp[1]=a1; rp[2]=a2; rp[3]=a3; rp[4]=a4;
        }
        __syncthreads();
        if (!ks) {
            #pragma unroll
            for (int j = 0; j < 3; ++j) {
                const float* rp = red + j*1280 + ridx;
                a0+=rp[0]; a1+=rp[1]; a2+=rp[2]; a3+=rp[3]; a4+=rp[4];
            }
            size_t off = (size_t)(b0+tb)*Hn + hg;
            if (t < Sn) {
                float xv = xseq[(b0+tb)*Sn + t];
                float gi = a0 + xv*p1[hg]      + p0[hg];
                float gf = a1 + xv*p1[Hn+hg]   + p0[Hn+hg];
                float gg = a2 + xv*p1[2*Hn+hg] + p0[2*Hn+hg];
                float go = a3 + xv*p1[3*Hn+hg] + p0[3*Hn+hg];
                float cn = sigf(gf)*cbuf[off] + sigf(gi)*tanhf(gg);
                float hn = sigf(go)*tanhf(cn);
                cbuf[off] = cn;
                cstore(hnext + off, hn);
            }
            if (t > 0) {
                size_t widx = ((size_t)(b0+tb)*Sn + (t-1))*Hn + hg;
                float val = a4 + b1[hg];
                if constexpr (WEF) ((float*)w1enc)[widx] = val;
                else               ((__half*)w1enc)[widx] = __float2half(val);
            }
        }
        ++bk;
        if (t == Sn) gbar_sys(gcnt, bk);   // w1enc handoff: wbl2 + inv (once)
        else         gbar(gcnt, bk);
        if (t < Sn) { float* tp = hprev; hprev = hnext; hnext = tp; }
    }

    // ================= decoder: 128 steps of LSTM -> q -> attention =========
    for (int t = 0; t < Sn; ++t) {
        // ---- dec LSTM ----
        STAGE_H(hprev);
        float a0=0.f,a1=0.f,a2=0.f,a3=0.f;
        {
            const float* hrow = hs + tb*HSTR + kofs;
            const float* w0 = Whh_d + (size_t)hg*Hn        + kofs;
            const float* w1r= Whh_d + (size_t)(Hn+hg)*Hn   + kofs;
            const float* w2r= Whh_d + (size_t)(2*Hn+hg)*Hn + kofs;
            const float* w3r= Whh_d + (size_t)(3*Hn+hg)*Hn + kofs;
            for (int i = 0; i < 128; i += 4) {
                float4 hv = *(const float4*)(hrow + i);
                float4 x0 = *(const float4*)(w0 + i);
                float4 x1 = *(const float4*)(w1r + i);
                float4 x2 = *(const float4*)(w2r + i);
                float4 x3 = *(const float4*)(w3r + i);
                a0 += hv.x*x0.x + hv.y*x0.y + hv.z*x0.z + hv.w*x0.w;
                a1 += hv.x*x1.x + hv.y*x1.y + hv.z*x1.z + hv.w*x1.w;
                a2 += hv.x*x2.x + hv.y*x2.y + hv.z*x2.z + hv.w*x2.w;
                a3 += hv.x*x3.x + hv.y*x3.y + hv.z*x3.z + hv.w*x3.w;
            }
        }
        if (ks) {
            float* rp = red + (ks-1)*1280 + ridx;
            rp[0]=a0; rp[1]=a1; rp[2]=a2; rp[3]=a3;
        }
        __syncthreads();
        if (!ks) {
            #pragma unroll
            for (int j = 0; j < 3; ++j) {
                const float* rp = red + j*1280 + ridx;
                a0+=rp[0]; a1+=rp[1]; a2+=rp[2]; a3+=rp[3];
            }
            size_t off = (size_t)(b0+tb)*Hn + hg;
            float xv = cload(x_in + b0 + tb);
            float gi = a0 + xv*r1[hg]      + r0[hg];
            float gf = a1 + xv*r1[Hn+hg]   + r0[Hn+hg];
            float gg = a2 + xv*r1[2*Hn+hg] + r0[2*Hn+hg];
            float go = a3 + xv*r1[3*Hn+hg] + r0[3*Hn+hg];
            float cn = sigf(gf)*cbuf[off] + sigf(gi)*tanhf(gg);
            float hn = sigf(go)*tanhf(cn);
            cbuf[off] = cn;
            cstore(hnext + off, hn);
        }
        ++bk; gbar(gcnt, bk);
        { float* tp = hprev; hprev = hnext; hnext = tp; }  // hprev = new hd

        // ---- q = hd @ W2^T + b2 ----
        STAGE_H(hprev);
        float qa = 0.f;
        {
            const float* hrow = hs + tb*HSTR + kofs;
            const float* wq = W2 + (size_t)hg*Hn + kofs;
            for (int i = 0; i < 128; i += 4) {
                float4 hv = *(const float4*)(hrow + i);
                float4 wv = *(const float4*)(wq + i);
                qa += hv.x*wv.x + hv.y*wv.y + hv.z*wv.z + hv.w*wv.w;
            }
        }
        if (ks) red[(ks-1)*1280 + ridx] = qa;
        __syncthreads();
        if (!ks) {
            #pragma unroll
            for (int j = 0; j < 3; ++j) qa += red[j*1280 + ridx];
            cstore(qbuf + (size_t)(b0+tb)*Hn + hg, qa + b2[hg]);
        }
        ++bk; gbar(gcnt, bk);

        // ---- attention + log_softmax + argmax + feedback (grp<8 only) ----
        if (grp < 8) {
            const int b = b0 + grp;
            if (tid < Hn) qs[tid] = cload(qbuf + (size_t)b*Hn + tid);
            else          vs[tid - Hn] = vv[tid - Hn];
            __syncthreads();
            const int wv2 = tid >> 6, l = tid & 63;
            const int kb = l << 3;
            float vreg[8], qreg[8];
            #pragma unroll
            for (int j = 0; j < 8; ++j) { vreg[j] = vs[kb+j]; qreg[j] = qs[kb+j]; }
            #pragma unroll
            for (int si = 0; si < 8; ++si) {
                const int s = (wv2 << 3) + si;
                float a = 0.f;
                if constexpr (WEF) {
                    const float* wr = (const float*)w1enc + ((size_t)b*Sn + s)*Hn + kb;
                    f4v w0 = __builtin_nontemporal_load((const f4v*)wr);
                    f4v w1v = __builtin_nontemporal_load((const f4v*)(wr + 4));
                    a += vreg[0]*tanhf(w0[0] + qreg[0]);
                    a += vreg[1]*tanhf(w0[1] + qreg[1]);
                    a += vreg[2]*tanhf(w0[2] + qreg[2]);
                    a += vreg[3]*tanhf(w0[3] + qreg[3]);
                    a += vreg[4]*tanhf(w1v[0] + qreg[4]);
                    a += vreg[5]*tanhf(w1v[1] + qreg[5]);
                    a += vreg[6]*tanhf(w1v[2] + qreg[6]);
                    a += vreg[7]*tanhf(w1v[3] + qreg[7]);
                } else {
                    const __half* wr = (const __half*)w1enc + ((size_t)b*Sn + s)*Hn + kb;
                    u4v u = __builtin_nontemporal_load((const u4v*)wr);
                    unsigned u0=u[0], u1=u[1], u2=u[2], u3=u[3];
                    float2 f0 = __half22float2(*(const __half2*)&u0);
                    float2 f1 = __half22float2(*(const __half2*)&u1);
                    float2 f2 = __half22float2(*(const __half2*)&u2);
                    float2 f3 = __half22float2(*(const __half2*)&u3);
                    a += vreg[0]*tanhf(f0.x + qreg[0]);
                    a += vreg[1]*tanhf(f0.y + qreg[1]);
                    a += vreg[2]*tanhf(f1.x + qreg[2]);
                    a += vreg[3]*tanhf(f1.y + qreg[3]);
                    a += vreg[4]*tanhf(f2.x + qreg[4]);
                    a += vreg[5]*tanhf(f2.y + qreg[5]);
                    a += vreg[6]*tanhf(f3.x + qreg[6]);
                    a += vreg[7]*tanhf(f3.y + qreg[7]);
                }
                a += __shfl_xor(a, 1);  a += __shfl_xor(a, 2);  a += __shfl_xor(a, 4);
                a += __shfl_xor(a, 8);  a += __shfl_xor(a, 16); a += __shfl_xor(a, 32);
                if (l == 0) us[s] = a;
            }
            __syncthreads();
            if (tid < 64) {
                float av = us[tid], c2 = us[tid+64];
                float mv; int mi;
                if (c2 > av) { mv = c2; mi = tid+64; } else { mv = av; mi = tid; }
                #pragma unroll
                for (int off2 = 1; off2 < 64; off2 <<= 1) {
                    float ov = __shfl_xor(mv, off2);
                    int   oi = __shfl_xor(mi, off2);
                    if (ov > mv || (ov == mv && oi < mi)) { mv = ov; mi = oi; }
                }
                float es = expf(av - mv) + expf(c2 - mv);
                #pragma unroll
                for (int off2 = 1; off2 < 64; off2 <<= 1) es += __shfl_xor(es, off2);
                if (tid == 0) {
                    rr[0] = mv; rr[1] = logf(es);
                    out_ptr[b*Sn + t] = (float)mi;
                    cstore(x_in + b, xseq[b*Sn + mi]);  // next decoder input
                }
            }
            __syncthreads();
            if (tid < Sn)
                out_scores[((size_t)b*Sn + t)*Sn + tid] = us[tid] - rr[0] - rr[1];
        }
        if (t < Sn-1) { ++bk; gbar(gcnt, bk); }
    }
#undef STAGE_H
}

extern "C" void kernel_launch(void* const* d_in, const int* in_sizes, int n_in,
                              void* d_out, int out_size, void* d_ws, size_t ws_size,
                              hipStream_t stream)
{
    const float* input_seq = (const float*)d_in[0];
    const float* We_e = (const float*)d_in[1],  *be_e = (const float*)d_in[2];
    const float* Wih_e = (const float*)d_in[3], *Whh_e = (const float*)d_in[4];
    const float* b_e = (const float*)d_in[5];
    const float* We_d = (const float*)d_in[6],  *be_d = (const float*)d_in[7];
    const float* Wih_d = (const float*)d_in[8], *Whh_d = (const float*)d_in[9];
    const float* b_d = (const float*)d_in[10];
    const float* W1 = (const float*)d_in[11], *b1 = (const float*)d_in[12];
    const float* W2 = (const float*)d_in[13], *b2 = (const float*)d_in[14];
    const float* v  = (const float*)d_in[15];  // bv cancels in log_softmax

    float* ws = (float*)d_ws;
    size_t o = 0;
    float* hb0  = ws + o; o += Bn*Hn;
    float* hb1  = ws + o; o += Bn*Hn;
    float* cbuf = ws + o; o += Bn*Hn;
    float* qbuf = ws + o; o += Bn*Hn;
    float* p1   = ws + o; o += G4;
    float* p0   = ws + o; o += G4;
    float* r1   = ws + o; o += G4;
    float* r0   = ws + o; o += G4;
    float* x_in = ws + o; o += 256;
    unsigned* barb = (unsigned*)(ws + o); o += 2048;   // 32 groups x 256B
    void* w1enc = (void*)(ws + o);
    const size_t w1enc_elems = (size_t)Bn*Sn*Hn;               // 16.8M
    const size_t need_f32 = (o + w1enc_elems) * sizeof(float); // ~69.2 MB
    const bool wf32 = (ws_size >= need_f32);

    hipMemsetAsync(hb0,  0, Bn*Hn*sizeof(float), stream);
    hipMemsetAsync(cbuf, 0, Bn*Hn*sizeof(float), stream);
    hipMemsetAsync(x_in, 0, (256+2048)*sizeof(float), stream); // x_in + barrier

    precompute_kernel<<<dim3(16), 256, 0, stream>>>(Wih_e, We_e, be_e, b_e,
                                                    Wih_d, We_d, be_d, b_d,
                                                    p1, p0, r1, r0);

    if (wf32)
        ptrnet_kernel<true ><<<dim3(NBLK), dim3(NTHR), 0, stream>>>(
            input_seq, Whh_e, Whh_d, W1, b1, W2, b2, v,
            p1, p0, r1, r0, hb0, hb1, cbuf, qbuf, x_in, w1enc, barb,
            (float*)d_out, (float*)d_out + (size_t)Bn*Sn*Sn);
    else
        ptrnet_kernel<false><<<dim3(NBLK), dim3(NTHR), 0, stream>>>(
            input_seq, Whh_e, Whh_d, W1, b1, W2, b2, v,
            p1, p0, r1, r0, hb0, hb1, cbuf, qbuf, x_in, w1enc, barb,
            (float*)d_out, (float*)d_out + (size_t)Bn*Sn*Sn);
}

// Round 9
// 24144.341 us; speedup vs baseline: 2.3793x; 2.3793x over previous
//
#include <hip/hip_runtime.h>
#include <hip/hip_fp16.h>

#define Bn 256
#define Sn 128
#define Hn 512
#define G4 2048
#define NBLK 256
#define NTHR 1024
#define HSTR 516   // padded LDS stride

typedef float f4v __attribute__((ext_vector_type(4)));
typedef unsigned u4v __attribute__((ext_vector_type(4)));

__device__ __forceinline__ float sigf(float x){
    float e = expf(-fabsf(x));
    float d = 1.f + e;
    return x >= 0.f ? 1.f/d : e/d;
}

// Agent-scope coherent access (coherence point, no L2 inv/wb).
__device__ __forceinline__ float cload(const float* p){
    return __hip_atomic_load((float*)p, __ATOMIC_RELAXED, __HIP_MEMORY_SCOPE_AGENT);
}
__device__ __forceinline__ float2 cload2(const float* p){
    union { unsigned long long u; float2 f; } cv;
    cv.u = __hip_atomic_load((const unsigned long long*)p, __ATOMIC_RELAXED,
                             __HIP_MEMORY_SCOPE_AGENT);
    return cv.f;
}
__device__ __forceinline__ void cstore(float* p, float v){
    __hip_atomic_store(p, v, __ATOMIC_RELAXED, __HIP_MEMORY_SCOPE_AGENT);
}

// ---- per-group (16 blocks, one batch-tile) barrier: relaxed, no cache ops.
__device__ __forceinline__ void gbar(unsigned* cnt, unsigned k){
    __syncthreads();
    if (threadIdx.x == 0) {
        __hip_atomic_fetch_add(cnt, 1u, __ATOMIC_RELAXED, __HIP_MEMORY_SCOPE_AGENT);
        while (__hip_atomic_load(cnt, __ATOMIC_RELAXED, __HIP_MEMORY_SCOPE_AGENT) < 16u*k)
            __builtin_amdgcn_s_sleep(1);
        asm volatile("" ::: "memory");
    }
    __syncthreads();
}
// Transition barrier (once): release (wbl2) + acquire (inv) for w1enc handoff.
__device__ __forceinline__ void gbar_sys(unsigned* cnt, unsigned k){
    __syncthreads();
    if (threadIdx.x == 0) {
        __hip_atomic_fetch_add(cnt, 1u, __ATOMIC_RELEASE, __HIP_MEMORY_SCOPE_AGENT);
        while (__hip_atomic_load(cnt, __ATOMIC_RELAXED, __HIP_MEMORY_SCOPE_AGENT) < 16u*k)
            __builtin_amdgcn_s_sleep(1);
        (void)__hip_atomic_load(cnt, __ATOMIC_ACQUIRE, __HIP_MEMORY_SCOPE_AGENT);
    }
    __syncthreads();
}

// ---- rank-1 collapse of the input-side GEMMs (F_IN == 1) ----
__global__ void precompute_kernel(
    const float* __restrict__ Wih_e, const float* __restrict__ We_e,
    const float* __restrict__ be_e,  const float* __restrict__ b_e,
    const float* __restrict__ Wih_d, const float* __restrict__ We_d,
    const float* __restrict__ be_d,  const float* __restrict__ b_d,
    float* __restrict__ p1, float* __restrict__ p0,
    float* __restrict__ r1, float* __restrict__ r0)
{
    int j = blockIdx.x*blockDim.x + threadIdx.x;   // 0..4095
    bool dec = j >= G4;
    int jj = dec ? j - G4 : j;
    const float* Wih = dec ? Wih_d : Wih_e;
    const float* We  = dec ? We_d  : We_e;
    const float* be  = dec ? be_d  : be_e;
    const float* bb  = dec ? b_d   : b_e;
    float s1 = 0.f, s0 = 0.f;
    for (int k = 0; k < Hn; ++k) {
        float w = Wih[jj*Hn + k];
        s1 += w * We[k];
        s0 += w * be[k];
    }
    s0 += bb[jj];
    if (dec) { r1[jj] = s1; r0[jj] = s0; }
    else     { p1[jj] = s1; p0[jj] = s0; }
}

// ---- whole pointer network, one persistent kernel ----
// 256 blocks (16 groups x 16): group bt owns batches [bt*16,+16); block grp
// owns h-slice [grp*32,+32). Decoder: 2 phases/step (LSTM+q-partial, attn).
template<bool WEF>
__global__ __launch_bounds__(NTHR, 4) void ptrnet_kernel(
    const float* __restrict__ xseq,
    const float* __restrict__ Whh_e, const float* __restrict__ Whh_d,
    const float* __restrict__ W1, const float* __restrict__ b1,
    const float* __restrict__ W2, const float* __restrict__ b2,
    const float* __restrict__ vv,
    const float* __restrict__ p1, const float* __restrict__ p0,
    const float* __restrict__ r1, const float* __restrict__ r0,
    float* __restrict__ hb0, float* __restrict__ hb1,
    float* __restrict__ cbuf, float* __restrict__ qpart,
    float* __restrict__ x_in, void* __restrict__ w1enc,
    unsigned* __restrict__ barb,
    float* __restrict__ out_scores, float* __restrict__ out_ptr)
{
    __shared__ float smem[16*HSTR + 512*5 + 16];   // 43.3 KB
    __shared__ float hs2[16*36 + 4];               // decoder hd tile (padded)
    float* hs  = smem;                 // [16][HSTR] h-tile
    float* red = smem + 16*HSTR;       // split-k partials
    float* qs  = smem;                 // attn aliases (phases disjoint)
    float* us  = smem + Hn;            // 128 logits
    float* rr  = smem + Hn + Sn + 8;   // {max, log-sum-exp}

    const int blk = blockIdx.x;
    const int tid = threadIdx.x;
    const int bt  = blk >> 4, grp = blk & 15;
    const int b0  = bt << 4;
    const int tb  = tid & 15;
    const int hh  = (tid >> 4) & 31;
    const int ks  = tid >> 9;
    const int hg  = (grp << 5) + hh;
    const int kofs = ks << 8;
    unsigned* gcnt = barb + bt*64;
    unsigned bk = 0;
    float* hprev = hb0;
    float* hnext = hb1;

    // v is loop-invariant: hoist per-lane slice into registers
    const int l64 = tid & 63;
    const int kb = l64 << 3;
    float vreg[8];
    #pragma unroll
    for (int j = 0; j < 8; ++j) vreg[j] = vv[kb+j];

#define STAGE_H(SRC) do { \
    for (int i_ = tid; i_ < 16*256; i_ += NTHR) { \
        int r_ = i_ >> 8, k2_ = (i_ & 255) << 1; \
        float2 v2_ = cload2((SRC) + (size_t)(b0+r_)*Hn + k2_); \
        hs[r_*HSTR + k2_] = v2_.x; hs[r_*HSTR + k2_ + 1] = v2_.y; \
    } __syncthreads(); } while(0)

    // ================= encoder: t = 0..128 (t==128 emits only w1enc[127]) ===
    for (int t = 0; t <= Sn; ++t) {
        STAGE_H(hprev);
        float a0=0.f,a1=0.f,a2=0.f,a3=0.f,a4=0.f;
        {
            const float* hrow = hs + tb*HSTR + kofs;
            const float* w0 = Whh_e + (size_t)hg*Hn          + kofs;
            const float* w1r= Whh_e + (size_t)(Hn+hg)*Hn     + kofs;
            const float* w2r= Whh_e + (size_t)(2*Hn+hg)*Hn   + kofs;
            const float* w3r= Whh_e + (size_t)(3*Hn+hg)*Hn   + kofs;
            const float* w4r= W1    + (size_t)hg*Hn          + kofs;
            for (int i = 0; i < 256; i += 4) {
                float4 hv = *(const float4*)(hrow + i);
                float4 x0 = *(const float4*)(w0 + i);
                float4 x1 = *(const float4*)(w1r + i);
                float4 x2 = *(const float4*)(w2r + i);
                float4 x3 = *(const float4*)(w3r + i);
                float4 x4 = *(const float4*)(w4r + i);
                a0 += hv.x*x0.x + hv.y*x0.y + hv.z*x0.z + hv.w*x0.w;
                a1 += hv.x*x1.x + hv.y*x1.y + hv.z*x1.z + hv.w*x1.w;
                a2 += hv.x*x2.x + hv.y*x2.y + hv.z*x2.z + hv.w*x2.w;
                a3 += hv.x*x3.x + hv.y*x3.y + hv.z*x3.z + hv.w*x3.w;
                a4 += hv.x*x4.x + hv.y*x4.y + hv.z*x4.z + hv.w*x4.w;
            }
        }
        if (ks) {
            float* rp = red + (size_t)(tid - 512)*5;
            rp[0]=a0; rp[1]=a1; rp[2]=a2; rp[3]=a3; rp[4]=a4;
        }
        __syncthreads();
        if (!ks) {
            const float* rp = red + (size_t)tid*5;
            a0+=rp[0]; a1+=rp[1]; a2+=rp[2]; a3+=rp[3]; a4+=rp[4];
            size_t off = (size_t)(b0+tb)*Hn + hg;
            if (t < Sn) {
                float xv = xseq[(b0+tb)*Sn + t];
                float gi = a0 + xv*p1[hg]      + p0[hg];
                float gf = a1 + xv*p1[Hn+hg]   + p0[Hn+hg];
                float gg = a2 + xv*p1[2*Hn+hg] + p0[2*Hn+hg];
                float go = a3 + xv*p1[3*Hn+hg] + p0[3*Hn+hg];
                float cn = sigf(gf)*cbuf[off] + sigf(gi)*tanhf(gg);
                float hn = sigf(go)*tanhf(cn);
                cbuf[off] = cn;
                cstore(hnext + off, hn);
            }
            if (t > 0) {
                size_t widx = ((size_t)(b0+tb)*Sn + (t-1))*Hn + hg;
                float val = a4 + b1[hg];
                if constexpr (WEF) ((float*)w1enc)[widx] = val;
                else               ((__half*)w1enc)[widx] = __float2half(val);
            }
        }
        ++bk;
        if (t == Sn) gbar_sys(gcnt, bk);   // w1enc handoff: wbl2 + inv (once)
        else         gbar(gcnt, bk);
        if (t < Sn) { float* tp = hprev; hprev = hnext; hnext = tp; }
    }

    // ================= decoder: 128 steps of (LSTM + q-partial) -> attn =====
    for (int t = 0; t < Sn; ++t) {
        // ---- dec LSTM ----
        STAGE_H(hprev);
        float a0=0.f,a1=0.f,a2=0.f,a3=0.f;
        {
            const float* hrow = hs + tb*HSTR + kofs;
            const float* w0 = Whh_d + (size_t)hg*Hn        + kofs;
            const float* w1r= Whh_d + (size_t)(Hn+hg)*Hn   + kofs;
            const float* w2r= Whh_d + (size_t)(2*Hn+hg)*Hn + kofs;
            const float* w3r= Whh_d + (size_t)(3*Hn+hg)*Hn + kofs;
            for (int i = 0; i < 256; i += 4) {
                float4 hv = *(const float4*)(hrow + i);
                float4 x0 = *(const float4*)(w0 + i);
                float4 x1 = *(const float4*)(w1r + i);
                float4 x2 = *(const float4*)(w2r + i);
                float4 x3 = *(const float4*)(w3r + i);
                a0 += hv.x*x0.x + hv.y*x0.y + hv.z*x0.z + hv.w*x0.w;
                a1 += hv.x*x1.x + hv.y*x1.y + hv.z*x1.z + hv.w*x1.w;
                a2 += hv.x*x2.x + hv.y*x2.y + hv.z*x2.z + hv.w*x2.w;
                a3 += hv.x*x3.x + hv.y*x3.y + hv.z*x3.z + hv.w*x3.w;
            }
        }
        if (ks) {
            float* rp = red + (size_t)(tid - 512)*4;
            rp[0]=a0; rp[1]=a1; rp[2]=a2; rp[3]=a3;
        }
        __syncthreads();
        if (!ks) {
            const float* rp = red + (size_t)tid*4;
            a0+=rp[0]; a1+=rp[1]; a2+=rp[2]; a3+=rp[3];
            size_t off = (size_t)(b0+tb)*Hn + hg;
            float xv = cload(x_in + b0 + tb);
            float gi = a0 + xv*r1[hg]      + r0[hg];
            float gf = a1 + xv*r1[Hn+hg]   + r0[Hn+hg];
            float gg = a2 + xv*r1[2*Hn+hg] + r0[2*Hn+hg];
            float go = a3 + xv*r1[3*Hn+hg] + r0[3*Hn+hg];
            float cn = sigf(gf)*cbuf[off] + sigf(gi)*tanhf(gg);
            float hn = sigf(go)*tanhf(cn);
            cbuf[off] = cn;
            cstore(hnext + off, hn);
            hs2[tb*36 + hh] = hn;          // local hd slice for q-partial
        }
        __syncthreads();
        // ---- q-partial: qpart[b][n][grp] = sum_{k in slice} hd[k]*W2[n,k] ----
        {
            const int tb2 = tid & 15;
            const int n0 = (tid >> 4) << 3;      // 0..504 step 8
            const float* h2 = hs2 + tb2*36;
            float4 h0 = *(const float4*)(h2+0),  h1 = *(const float4*)(h2+4);
            float4 h2v= *(const float4*)(h2+8),  h3 = *(const float4*)(h2+12);
            float4 h4 = *(const float4*)(h2+16), h5 = *(const float4*)(h2+20);
            float4 h6 = *(const float4*)(h2+24), h7 = *(const float4*)(h2+28);
            float* qp = qpart + ((size_t)(b0+tb2)*Hn + n0)*16 + grp;
            #pragma unroll
            for (int n = 0; n < 8; ++n) {
                const float* wr = W2 + (size_t)(n0+n)*Hn + (grp<<5);
                float4 w0 = *(const float4*)(wr+0),  w1v= *(const float4*)(wr+4);
                float4 w2v= *(const float4*)(wr+8),  w3v= *(const float4*)(wr+12);
                float acc = h0.x*w0.x + h0.y*w0.y + h0.z*w0.z + h0.w*w0.w
                          + h1.x*w1v.x+ h1.y*w1v.y+ h1.z*w1v.z+ h1.w*w1v.w
                          + h2v.x*w2v.x+h2v.y*w2v.y+h2v.z*w2v.z+h2v.w*w2v.w
                          + h3.x*w3v.x+ h3.y*w3v.y+ h3.z*w3v.z+ h3.w*w3v.w;
                float4 w4 = *(const float4*)(wr+16), w5 = *(const float4*)(wr+20);
                float4 w6 = *(const float4*)(wr+24), w7 = *(const float4*)(wr+28);
                acc += h4.x*w4.x + h4.y*w4.y + h4.z*w4.z + h4.w*w4.w
                     + h5.x*w5.x + h5.y*w5.y + h5.z*w5.z + h5.w*w5.w
                     + h6.x*w6.x + h6.y*w6.y + h6.z*w6.z + h6.w*w6.w
                     + h7.x*w7.x + h7.y*w7.y + h7.z*w7.z + h7.w*w7.w;
                cstore(qp + (size_t)n*16, acc);
            }
        }
        ++bk; gbar(gcnt, bk);
        { float* tp = hprev; hprev = hnext; hnext = tp; }  // hprev = new hd

        // ---- attention + log_softmax + argmax + feedback (block = batch) ----
        const int b = blk;
        if (tid < Hn) {   // sum the 16 q-partials for output dim n = tid
            const float* qp = qpart + ((size_t)b*Hn + tid)*16;
            float s = b2[tid];
            #pragma unroll
            for (int j = 0; j < 16; j += 2) { float2 v2 = cload2(qp + j); s += v2.x + v2.y; }
            qs[tid] = s;
        }
        __syncthreads();
        const int wv2 = tid >> 6;
        float qreg[8];
        #pragma unroll
        for (int j = 0; j < 8; ++j) qreg[j] = qs[kb+j];
        #pragma unroll
        for (int si = 0; si < 8; ++si) {
            const int s = (wv2 << 3) + si;
            float a = 0.f;
            if constexpr (WEF) {
                const float* wr = (const float*)w1enc + ((size_t)b*Sn + s)*Hn + kb;
                f4v w0 = *(const f4v*)wr;
                f4v w1v = *(const f4v*)(wr + 4);
                a += vreg[0]*tanhf(w0[0] + qreg[0]);
                a += vreg[1]*tanhf(w0[1] + qreg[1]);
                a += vreg[2]*tanhf(w0[2] + qreg[2]);
                a += vreg[3]*tanhf(w0[3] + qreg[3]);
                a += vreg[4]*tanhf(w1v[0] + qreg[4]);
                a += vreg[5]*tanhf(w1v[1] + qreg[5]);
                a += vreg[6]*tanhf(w1v[2] + qreg[6]);
                a += vreg[7]*tanhf(w1v[3] + qreg[7]);
            } else {
                const __half* wr = (const __half*)w1enc + ((size_t)b*Sn + s)*Hn + kb;
                u4v u = *(const u4v*)wr;
                unsigned u0=u[0], u1=u[1], u2=u[2], u3=u[3];
                float2 f0 = __half22float2(*(const __half2*)&u0);
                float2 f1 = __half22float2(*(const __half2*)&u1);
                float2 f2 = __half22float2(*(const __half2*)&u2);
                float2 f3 = __half22float2(*(const __half2*)&u3);
                a += vreg[0]*tanhf(f0.x + qreg[0]);
                a += vreg[1]*tanhf(f0.y + qreg[1]);
                a += vreg[2]*tanhf(f1.x + qreg[2]);
                a += vreg[3]*tanhf(f1.y + qreg[3]);
                a += vreg[4]*tanhf(f2.x + qreg[4]);
                a += vreg[5]*tanhf(f2.y + qreg[5]);
                a += vreg[6]*tanhf(f3.x + qreg[6]);
                a += vreg[7]*tanhf(f3.y + qreg[7]);
            }
            a += __shfl_xor(a, 1);  a += __shfl_xor(a, 2);  a += __shfl_xor(a, 4);
            a += __shfl_xor(a, 8);  a += __shfl_xor(a, 16); a += __shfl_xor(a, 32);
            if (l64 == 0) us[s] = a;
        }
        __syncthreads();
        if (tid < 64) {
            float av = us[tid], c2 = us[tid+64];
            float mv; int mi;
            if (c2 > av) { mv = c2; mi = tid+64; } else { mv = av; mi = tid; }
            #pragma unroll
            for (int off2 = 1; off2 < 64; off2 <<= 1) {
                float ov = __shfl_xor(mv, off2);
                int   oi = __shfl_xor(mi, off2);
                if (ov > mv || (ov == mv && oi < mi)) { mv = ov; mi = oi; }
            }
            float es = expf(av - mv) + expf(c2 - mv);
            #pragma unroll
            for (int off2 = 1; off2 < 64; off2 <<= 1) es += __shfl_xor(es, off2);
            if (tid == 0) {
                rr[0] = mv; rr[1] = logf(es);
                out_ptr[b*Sn + t] = (float)mi;
                cstore(x_in + b, xseq[b*Sn + mi]);  // next decoder input
            }
        }
        __syncthreads();
        if (tid < Sn)
            out_scores[((size_t)b*Sn + t)*Sn + tid] = us[tid] - rr[0] - rr[1];
        if (t < Sn-1) { ++bk; gbar(gcnt, bk); }
    }
#undef STAGE_H
}

extern "C" void kernel_launch(void* const* d_in, const int* in_sizes, int n_in,
                              void* d_out, int out_size, void* d_ws, size_t ws_size,
                              hipStream_t stream)
{
    const float* input_seq = (const float*)d_in[0];
    const float* We_e = (const float*)d_in[1],  *be_e = (const float*)d_in[2];
    const float* Wih_e = (const float*)d_in[3], *Whh_e = (const float*)d_in[4];
    const float* b_e = (const float*)d_in[5];
    const float* We_d = (const float*)d_in[6],  *be_d = (const float*)d_in[7];
    const float* Wih_d = (const float*)d_in[8], *Whh_d = (const float*)d_in[9];
    const float* b_d = (const float*)d_in[10];
    const float* W1 = (const float*)d_in[11], *b1 = (const float*)d_in[12];
    const float* W2 = (const float*)d_in[13], *b2 = (const float*)d_in[14];
    const float* v  = (const float*)d_in[15];  // bv cancels in log_softmax

    float* ws = (float*)d_ws;
    size_t o = 0;
    float* hb0  = ws + o; o += Bn*Hn;
    float* hb1  = ws + o; o += Bn*Hn;
    float* cbuf = ws + o; o += Bn*Hn;
    float* p1   = ws + o; o += G4;
    float* p0   = ws + o; o += G4;
    float* r1   = ws + o; o += G4;
    float* r0   = ws + o; o += G4;
    float* x_in = ws + o; o += 256;
    unsigned* barb = (unsigned*)(ws + o); o += 1024;   // 16 groups x 256B
    float* qpart = ws + o; o += (size_t)Bn*Hn*16;      // 8 MB q-partials
    void* w1enc = (void*)(ws + o);
    const size_t w1enc_elems = (size_t)Bn*Sn*Hn;               // 16.8M
    const size_t need_f32 = (o + w1enc_elems) * sizeof(float); // ~77 MB
    const bool wf32 = (ws_size >= need_f32);

    hipMemsetAsync(hb0,  0, Bn*Hn*sizeof(float), stream);
    hipMemsetAsync(cbuf, 0, Bn*Hn*sizeof(float), stream);
    hipMemsetAsync(x_in, 0, (256+1024)*sizeof(float), stream); // x_in + barrier

    precompute_kernel<<<dim3(16), 256, 0, stream>>>(Wih_e, We_e, be_e, b_e,
                                                    Wih_d, We_d, be_d, b_d,
                                                    p1, p0, r1, r0);

    if (wf32)
        ptrnet_kernel<true ><<<dim3(NBLK), dim3(NTHR), 0, stream>>>(
            input_seq, Whh_e, Whh_d, W1, b1, W2, b2, v,
            p1, p0, r1, r0, hb0, hb1, cbuf, qpart, x_in, w1enc, barb,
            (float*)d_out, (float*)d_out + (size_t)Bn*Sn*Sn);
    else
        ptrnet_kernel<false><<<dim3(NBLK), dim3(NTHR), 0, stream>>>(
            input_seq, Whh_e, Whh_d, W1, b1, W2, b2, v,
            p1, p0, r1, r0, hb0, hb1, cbuf, qpart, x_in, w1enc, barb,
            (float*)d_out, (float*)d_out + (size_t)Bn*Sn*Sn);
}

// Round 10
// 12955.316 us; speedup vs baseline: 4.4342x; 1.8637x over previous
//
#include <hip/hip_runtime.h>
#include <hip/hip_fp16.h>

#define Bn 256
#define Sn 128
#define Hn 512
#define G4 2048
#define NBLK 256
#define NTHR 1024
#define HSTR 516   // padded LDS stride

typedef float f4v __attribute__((ext_vector_type(4)));
typedef unsigned u4v __attribute__((ext_vector_type(4)));

__device__ __forceinline__ float sigf(float x){
    float e = expf(-fabsf(x));
    float d = 1.f + e;
    return x >= 0.f ? 1.f/d : e/d;
}

// Agent-scope coherent scalar access (coherence point, no L2 inv/wb).
__device__ __forceinline__ float cload(const float* p){
    return __hip_atomic_load((float*)p, __ATOMIC_RELAXED, __HIP_MEMORY_SCOPE_AGENT);
}
__device__ __forceinline__ void cstore(float* p, float v){
    __hip_atomic_store(p, v, __ATOMIC_RELAXED, __HIP_MEMORY_SCOPE_AGENT);
}
// Wide coherence-point load: volatile lowers to global_load_dwordx4 sc0 sc1
// on gfx940+ (AMDGPUUsage memory model) — 16B per fabric transaction.
__device__ __forceinline__ f4v vload4(const float* p){
    return *(volatile const f4v*)p;
}

// ---- per-group (16 blocks, one batch-tile) barrier: relaxed, no cache ops.
__device__ __forceinline__ void gbar(unsigned* cnt, unsigned k){
    __syncthreads();
    if (threadIdx.x == 0) {
        __hip_atomic_fetch_add(cnt, 1u, __ATOMIC_RELAXED, __HIP_MEMORY_SCOPE_AGENT);
        while (__hip_atomic_load(cnt, __ATOMIC_RELAXED, __HIP_MEMORY_SCOPE_AGENT) < 16u*k)
            __builtin_amdgcn_s_sleep(1);
        asm volatile("" ::: "memory");
    }
    __syncthreads();
}
// Transition barrier (once): release (wbl2) + acquire (inv) for w1enc handoff.
__device__ __forceinline__ void gbar_sys(unsigned* cnt, unsigned k){
    __syncthreads();
    if (threadIdx.x == 0) {
        __hip_atomic_fetch_add(cnt, 1u, __ATOMIC_RELEASE, __HIP_MEMORY_SCOPE_AGENT);
        while (__hip_atomic_load(cnt, __ATOMIC_RELAXED, __HIP_MEMORY_SCOPE_AGENT) < 16u*k)
            __builtin_amdgcn_s_sleep(1);
        (void)__hip_atomic_load(cnt, __ATOMIC_ACQUIRE, __HIP_MEMORY_SCOPE_AGENT);
    }
    __syncthreads();
}

// ---- rank-1 collapse of the input-side GEMMs (F_IN == 1) ----
__global__ void precompute_kernel(
    const float* __restrict__ Wih_e, const float* __restrict__ We_e,
    const float* __restrict__ be_e,  const float* __restrict__ b_e,
    const float* __restrict__ Wih_d, const float* __restrict__ We_d,
    const float* __restrict__ be_d,  const float* __restrict__ b_d,
    float* __restrict__ p1, float* __restrict__ p0,
    float* __restrict__ r1, float* __restrict__ r0)
{
    int j = blockIdx.x*blockDim.x + threadIdx.x;   // 0..4095
    bool dec = j >= G4;
    int jj = dec ? j - G4 : j;
    const float* Wih = dec ? Wih_d : Wih_e;
    const float* We  = dec ? We_d  : We_e;
    const float* be  = dec ? be_d  : be_e;
    const float* bb  = dec ? b_d   : b_e;
    float s1 = 0.f, s0 = 0.f;
    for (int k = 0; k < Hn; ++k) {
        float w = Wih[jj*Hn + k];
        s1 += w * We[k];
        s0 += w * be[k];
    }
    s0 += bb[jj];
    if (dec) { r1[jj] = s1; r0[jj] = s0; }
    else     { p1[jj] = s1; p0[jj] = s0; }
}

// ---- whole pointer network, one persistent kernel (r7 structure) ----
template<bool WEF>
__global__ __launch_bounds__(NTHR, 4) void ptrnet_kernel(
    const float* __restrict__ xseq,
    const float* __restrict__ Whh_e, const float* __restrict__ Whh_d,
    const float* __restrict__ W1, const float* __restrict__ b1,
    const float* __restrict__ W2, const float* __restrict__ b2,
    const float* __restrict__ vv,
    const float* __restrict__ p1, const float* __restrict__ p0,
    const float* __restrict__ r1, const float* __restrict__ r0,
    float* __restrict__ hb0, float* __restrict__ hb1,
    float* __restrict__ cbuf, float* __restrict__ qbuf,
    float* __restrict__ x_in, void* __restrict__ w1enc,
    unsigned* __restrict__ barb,
    float* __restrict__ out_scores, float* __restrict__ out_ptr)
{
    __shared__ float smem[16*HSTR + 512*5 + 16];   // 43.3 KB
    float* hs  = smem;                 // [16][HSTR] h-tile
    float* red = smem + 16*HSTR;       // split-k partials
    float* qs  = smem;                 // attn aliases (phases disjoint)
    float* us  = smem + Hn;            // 128 logits
    float* rr  = smem + Hn + Sn + 8;   // {max, log-sum-exp}

    const int blk = blockIdx.x;
    const int tid = threadIdx.x;
    const int bt  = blk >> 4, grp = blk & 15;
    const int b0  = bt << 4;
    const int tb  = tid & 15;
    const int hh  = (tid >> 4) & 31;
    const int ks  = tid >> 9;
    const int hg  = (grp << 5) + hh;
    const int kofs = ks << 8;
    unsigned* gcnt = barb + bt*64;
    unsigned bk = 0;
    float* hprev = hb0;
    float* hnext = hb1;

    // v is loop-invariant: hoist per-lane slice into registers
    const int l64 = tid & 63;
    const int kb = l64 << 3;
    float vreg[8];
    #pragma unroll
    for (int j = 0; j < 8; ++j) vreg[j] = vv[kb+j];

// 16 rows x 512 floats = 2048 float4s over 1024 threads: 2 wide coherent
// loads per thread (16B sc0/sc1 transactions).
#define STAGE_H(SRC) do { \
    for (int i_ = tid; i_ < 16*128; i_ += NTHR) { \
        int r_ = i_ >> 7; int c4_ = (i_ & 127) << 2; \
        f4v v4_ = vload4((SRC) + (size_t)(b0+r_)*Hn + c4_); \
        *(f4v*)(hs + r_*HSTR + c4_) = v4_; \
    } __syncthreads(); } while(0)

    // ================= encoder: t = 0..128 (t==128 emits only w1enc[127]) ===
    for (int t = 0; t <= Sn; ++t) {
        STAGE_H(hprev);
        float a0=0.f,a1=0.f,a2=0.f,a3=0.f,a4=0.f;
        {
            const float* hrow = hs + tb*HSTR + kofs;
            const float* w0 = Whh_e + (size_t)hg*Hn          + kofs;
            const float* w1r= Whh_e + (size_t)(Hn+hg)*Hn     + kofs;
            const float* w2r= Whh_e + (size_t)(2*Hn+hg)*Hn   + kofs;
            const float* w3r= Whh_e + (size_t)(3*Hn+hg)*Hn   + kofs;
            const float* w4r= W1    + (size_t)hg*Hn          + kofs;
            for (int i = 0; i < 256; i += 4) {
                float4 hv = *(const float4*)(hrow + i);
                float4 x0 = *(const float4*)(w0 + i);
                float4 x1 = *(const float4*)(w1r + i);
                float4 x2 = *(const float4*)(w2r + i);
                float4 x3 = *(const float4*)(w3r + i);
                float4 x4 = *(const float4*)(w4r + i);
                a0 += hv.x*x0.x + hv.y*x0.y + hv.z*x0.z + hv.w*x0.w;
                a1 += hv.x*x1.x + hv.y*x1.y + hv.z*x1.z + hv.w*x1.w;
                a2 += hv.x*x2.x + hv.y*x2.y + hv.z*x2.z + hv.w*x2.w;
                a3 += hv.x*x3.x + hv.y*x3.y + hv.z*x3.z + hv.w*x3.w;
                a4 += hv.x*x4.x + hv.y*x4.y + hv.z*x4.z + hv.w*x4.w;
            }
        }
        if (ks) {
            float* rp = red + (size_t)(tid - 512)*5;
            rp[0]=a0; rp[1]=a1; rp[2]=a2; rp[3]=a3; rp[4]=a4;
        }
        __syncthreads();
        if (!ks) {
            const float* rp = red + (size_t)tid*5;
            a0+=rp[0]; a1+=rp[1]; a2+=rp[2]; a3+=rp[3]; a4+=rp[4];
            size_t off = (size_t)(b0+tb)*Hn + hg;
            if (t < Sn) {
                float xv = xseq[(b0+tb)*Sn + t];
                float gi = a0 + xv*p1[hg]      + p0[hg];
                float gf = a1 + xv*p1[Hn+hg]   + p0[Hn+hg];
                float gg = a2 + xv*p1[2*Hn+hg] + p0[2*Hn+hg];
                float go = a3 + xv*p1[3*Hn+hg] + p0[3*Hn+hg];
                float cn = sigf(gf)*cbuf[off] + sigf(gi)*tanhf(gg);
                float hn = sigf(go)*tanhf(cn);
                cbuf[off] = cn;
                cstore(hnext + off, hn);
            }
            if (t > 0) {
                size_t widx = ((size_t)(b0+tb)*Sn + (t-1))*Hn + hg;
                float val = a4 + b1[hg];
                if constexpr (WEF) ((float*)w1enc)[widx] = val;
                else               ((__half*)w1enc)[widx] = __float2half(val);
            }
        }
        ++bk;
        if (t == Sn) gbar_sys(gcnt, bk);   // w1enc handoff: wbl2 + inv (once)
        else         gbar(gcnt, bk);
        if (t < Sn) { float* tp = hprev; hprev = hnext; hnext = tp; }
    }

    // ================= decoder: 128 steps of LSTM -> q -> attention =========
    for (int t = 0; t < Sn; ++t) {
        // ---- dec LSTM ----
        STAGE_H(hprev);
        float a0=0.f,a1=0.f,a2=0.f,a3=0.f;
        {
            const float* hrow = hs + tb*HSTR + kofs;
            const float* w0 = Whh_d + (size_t)hg*Hn        + kofs;
            const float* w1r= Whh_d + (size_t)(Hn+hg)*Hn   + kofs;
            const float* w2r= Whh_d + (size_t)(2*Hn+hg)*Hn + kofs;
            const float* w3r= Whh_d + (size_t)(3*Hn+hg)*Hn + kofs;
            for (int i = 0; i < 256; i += 4) {
                float4 hv = *(const float4*)(hrow + i);
                float4 x0 = *(const float4*)(w0 + i);
                float4 x1 = *(const float4*)(w1r + i);
                float4 x2 = *(const float4*)(w2r + i);
                float4 x3 = *(const float4*)(w3r + i);
                a0 += hv.x*x0.x + hv.y*x0.y + hv.z*x0.z + hv.w*x0.w;
                a1 += hv.x*x1.x + hv.y*x1.y + hv.z*x1.z + hv.w*x1.w;
                a2 += hv.x*x2.x + hv.y*x2.y + hv.z*x2.z + hv.w*x2.w;
                a3 += hv.x*x3.x + hv.y*x3.y + hv.z*x3.z + hv.w*x3.w;
            }
        }
        if (ks) {
            float* rp = red + (size_t)(tid - 512)*4;
            rp[0]=a0; rp[1]=a1; rp[2]=a2; rp[3]=a3;
        }
        __syncthreads();
        if (!ks) {
            const float* rp = red + (size_t)tid*4;
            a0+=rp[0]; a1+=rp[1]; a2+=rp[2]; a3+=rp[3];
            size_t off = (size_t)(b0+tb)*Hn + hg;
            float xv = cload(x_in + b0 + tb);
            float gi = a0 + xv*r1[hg]      + r0[hg];
            float gf = a1 + xv*r1[Hn+hg]   + r0[Hn+hg];
            float gg = a2 + xv*r1[2*Hn+hg] + r0[2*Hn+hg];
            float go = a3 + xv*r1[3*Hn+hg] + r0[3*Hn+hg];
            float cn = sigf(gf)*cbuf[off] + sigf(gi)*tanhf(gg);
            float hn = sigf(go)*tanhf(cn);
            cbuf[off] = cn;
            cstore(hnext + off, hn);
        }
        ++bk; gbar(gcnt, bk);
        { float* tp = hprev; hprev = hnext; hnext = tp; }  // hprev = new hd

        // ---- q = hd @ W2^T + b2 ----
        STAGE_H(hprev);
        float qa = 0.f;
        {
            const float* hrow = hs + tb*HSTR + kofs;
            const float* wq = W2 + (size_t)hg*Hn + kofs;
            for (int i = 0; i < 256; i += 4) {
                float4 hv = *(const float4*)(hrow + i);
                float4 wv = *(const float4*)(wq + i);
                qa += hv.x*wv.x + hv.y*wv.y + hv.z*wv.z + hv.w*wv.w;
            }
        }
        if (ks) red[tid - 512] = qa;
        __syncthreads();
        if (!ks) cstore(qbuf + (size_t)(b0+tb)*Hn + hg, qa + red[tid] + b2[hg]);
        ++bk; gbar(gcnt, bk);

        // ---- attention + log_softmax + argmax + feedback (block = batch) ----
        const int b = blk;
        if (tid < 128) {   // 512 floats of q via 128 wide coherent loads
            f4v q4 = vload4(qbuf + (size_t)b*Hn + (tid << 2));
            *(f4v*)(qs + (tid << 2)) = q4;
        }
        __syncthreads();
        const int wv2 = tid >> 6;
        float qreg[8];
        #pragma unroll
        for (int j = 0; j < 8; ++j) qreg[j] = qs[kb+j];
        #pragma unroll
        for (int si = 0; si < 8; ++si) {
            const int s = (wv2 << 3) + si;
            float a = 0.f;
            if constexpr (WEF) {
                const float* wr = (const float*)w1enc + ((size_t)b*Sn + s)*Hn + kb;
                f4v w0 = *(const f4v*)wr;
                f4v w1v = *(const f4v*)(wr + 4);
                a += vreg[0]*tanhf(w0[0] + qreg[0]);
                a += vreg[1]*tanhf(w0[1] + qreg[1]);
                a += vreg[2]*tanhf(w0[2] + qreg[2]);
                a += vreg[3]*tanhf(w0[3] + qreg[3]);
                a += vreg[4]*tanhf(w1v[0] + qreg[4]);
                a += vreg[5]*tanhf(w1v[1] + qreg[5]);
                a += vreg[6]*tanhf(w1v[2] + qreg[6]);
                a += vreg[7]*tanhf(w1v[3] + qreg[7]);
            } else {
                const __half* wr = (const __half*)w1enc + ((size_t)b*Sn + s)*Hn + kb;
                u4v u = *(const u4v*)wr;
                unsigned u0=u[0], u1=u[1], u2=u[2], u3=u[3];
                float2 f0 = __half22float2(*(const __half2*)&u0);
                float2 f1 = __half22float2(*(const __half2*)&u1);
                float2 f2 = __half22float2(*(const __half2*)&u2);
                float2 f3 = __half22float2(*(const __half2*)&u3);
                a += vreg[0]*tanhf(f0.x + qreg[0]);
                a += vreg[1]*tanhf(f0.y + qreg[1]);
                a += vreg[2]*tanhf(f1.x + qreg[2]);
                a += vreg[3]*tanhf(f1.y + qreg[3]);
                a += vreg[4]*tanhf(f2.x + qreg[4]);
                a += vreg[5]*tanhf(f2.y + qreg[5]);
                a += vreg[6]*tanhf(f3.x + qreg[6]);
                a += vreg[7]*tanhf(f3.y + qreg[7]);
            }
            a += __shfl_xor(a, 1);  a += __shfl_xor(a, 2);  a += __shfl_xor(a, 4);
            a += __shfl_xor(a, 8);  a += __shfl_xor(a, 16); a += __shfl_xor(a, 32);
            if (l64 == 0) us[s] = a;
        }
        __syncthreads();
        if (tid < 64) {
            float av = us[tid], c2 = us[tid+64];
            float mv; int mi;
            if (c2 > av) { mv = c2; mi = tid+64; } else { mv = av; mi = tid; }
            #pragma unroll
            for (int off2 = 1; off2 < 64; off2 <<= 1) {
                float ov = __shfl_xor(mv, off2);
                int   oi = __shfl_xor(mi, off2);
                if (ov > mv || (ov == mv && oi < mi)) { mv = ov; mi = oi; }
            }
            float es = expf(av - mv) + expf(c2 - mv);
            #pragma unroll
            for (int off2 = 1; off2 < 64; off2 <<= 1) es += __shfl_xor(es, off2);
            if (tid == 0) {
                rr[0] = mv; rr[1] = logf(es);
                out_ptr[b*Sn + t] = (float)mi;
                cstore(x_in + b, xseq[b*Sn + mi]);  // next decoder input
            }
        }
        __syncthreads();
        if (tid < Sn)
            out_scores[((size_t)b*Sn + t)*Sn + tid] = us[tid] - rr[0] - rr[1];
        if (t < Sn-1) { ++bk; gbar(gcnt, bk); }
    }
#undef STAGE_H
}

extern "C" void kernel_launch(void* const* d_in, const int* in_sizes, int n_in,
                              void* d_out, int out_size, void* d_ws, size_t ws_size,
                              hipStream_t stream)
{
    const float* input_seq = (const float*)d_in[0];
    const float* We_e = (const float*)d_in[1],  *be_e = (const float*)d_in[2];
    const float* Wih_e = (const float*)d_in[3], *Whh_e = (const float*)d_in[4];
    const float* b_e = (const float*)d_in[5];
    const float* We_d = (const float*)d_in[6],  *be_d = (const float*)d_in[7];
    const float* Wih_d = (const float*)d_in[8], *Whh_d = (const float*)d_in[9];
    const float* b_d = (const float*)d_in[10];
    const float* W1 = (const float*)d_in[11], *b1 = (const float*)d_in[12];
    const float* W2 = (const float*)d_in[13], *b2 = (const float*)d_in[14];
    const float* v  = (const float*)d_in[15];  // bv cancels in log_softmax

    float* ws = (float*)d_ws;
    size_t o = 0;
    float* hb0  = ws + o; o += Bn*Hn;
    float* hb1  = ws + o; o += Bn*Hn;
    float* cbuf = ws + o; o += Bn*Hn;
    float* qbuf = ws + o; o += Bn*Hn;
    float* p1   = ws + o; o += G4;
    float* p0   = ws + o; o += G4;
    float* r1   = ws + o; o += G4;
    float* r0   = ws + o; o += G4;
    float* x_in = ws + o; o += 256;
    unsigned* barb = (unsigned*)(ws + o); o += 1024;   // 16 groups x 256B
    void* w1enc = (void*)(ws + o);
    const size_t w1enc_elems = (size_t)Bn*Sn*Hn;               // 16.8M
    const size_t need_f32 = (o + w1enc_elems) * sizeof(float); // ~69.2 MB
    const bool wf32 = (ws_size >= need_f32);

    hipMemsetAsync(hb0,  0, Bn*Hn*sizeof(float), stream);
    hipMemsetAsync(cbuf, 0, Bn*Hn*sizeof(float), stream);
    hipMemsetAsync(x_in, 0, (256+1024)*sizeof(float), stream); // x_in + barrier

    precompute_kernel<<<dim3(16), 256, 0, stream>>>(Wih_e, We_e, be_e, b_e,
                                                    Wih_d, We_d, be_d, b_d,
                                                    p1, p0, r1, r0);

    if (wf32)
        ptrnet_kernel<true ><<<dim3(NBLK), dim3(NTHR), 0, stream>>>(
            input_seq, Whh_e, Whh_d, W1, b1, W2, b2, v,
            p1, p0, r1, r0, hb0, hb1, cbuf, qbuf, x_in, w1enc, barb,
            (float*)d_out, (float*)d_out + (size_t)Bn*Sn*Sn);
    else
        ptrnet_kernel<false><<<dim3(NBLK), dim3(NTHR), 0, stream>>>(
            input_seq, Whh_e, Whh_d, W1, b1, W2, b2, v,
            p1, p0, r1, r0, hb0, hb1, cbuf, qbuf, x_in, w1enc, barb,
            (float*)d_out, (float*)d_out + (size_t)Bn*Sn*Sn);
}